// Round 1
// baseline (524.596 us; speedup 1.0000x reference)
//
#include <hip/hip_runtime.h>
#include <hip/hip_bf16.h>

#define N_NODES 50000
#define N_RELS 8
#define IN_DIM 128
#define OUT_DIM 128
#define N_EDGES 800000
#define NR (N_NODES * N_RELS)              /* 400000 keys (tgt*8+rel) */
#define KDIM (N_RELS * IN_DIM)             /* 1024 = GEMM K */
#define NODES_PER_BLOCK 32
#define SCAN_ELEMS 2048
#define SCAN_NBLK ((NR + SCAN_ELEMS - 1) / SCAN_ELEMS)  /* 196 */

typedef __attribute__((ext_vector_type(8))) short bf16x8;
typedef __attribute__((ext_vector_type(4))) float floatx4;

__device__ inline unsigned short f2bf(float f) {
    unsigned u = __builtin_bit_cast(unsigned, f);
    u += 0x7fff + ((u >> 16) & 1);   // round-to-nearest-even
    return (unsigned short)(u >> 16);
}

// ---------------- sort pipeline ----------------

__global__ void count_kernel(const int* __restrict__ tri, int* __restrict__ cnt) {
    int e = blockIdx.x * 256 + threadIdx.x;
    if (e >= N_EDGES) return;
    int rel = tri[3 * e + 1];
    int tgt = tri[3 * e + 2];
    atomicAdd(&cnt[tgt * N_RELS + rel], 1);
}

__global__ void scan_part(const int* __restrict__ cnt, int* __restrict__ bsum) {
    __shared__ int s[256];
    int b = blockIdx.x, t = threadIdx.x;
    int base = b * SCAN_ELEMS + t * 8;
    int sum = 0;
#pragma unroll
    for (int k = 0; k < 8; ++k) {
        int i = base + k;
        sum += (i < NR) ? cnt[i] : 0;
    }
    s[t] = sum; __syncthreads();
    for (int off = 128; off > 0; off >>= 1) {
        if (t < off) s[t] += s[t + off];
        __syncthreads();
    }
    if (t == 0) bsum[b] = s[0];
}

__global__ void scan_mid(const int* __restrict__ bsum, int* __restrict__ boff) {
    __shared__ int s[256];
    int t = threadIdx.x;
    int v = (t < SCAN_NBLK) ? bsum[t] : 0;
    s[t] = v; __syncthreads();
    for (int off = 1; off < 256; off <<= 1) {
        int x = (t >= off) ? s[t - off] : 0;
        __syncthreads();
        s[t] += x;
        __syncthreads();
    }
    if (t < SCAN_NBLK) boff[t] = s[t] - v;   // exclusive
}

__global__ void scan_apply(const int* __restrict__ cnt, const int* __restrict__ boff,
                           int* __restrict__ segOff, int* __restrict__ cursor) {
    __shared__ int s[256];
    int b = blockIdx.x, t = threadIdx.x;
    int base = b * SCAN_ELEMS + t * 8;
    int v[8]; int sum = 0;
#pragma unroll
    for (int k = 0; k < 8; ++k) {
        int i = base + k;
        v[k] = (i < NR) ? cnt[i] : 0;
        sum += v[k];
    }
    s[t] = sum; __syncthreads();
    for (int off = 1; off < 256; off <<= 1) {
        int x = (t >= off) ? s[t - off] : 0;
        __syncthreads();
        s[t] += x;
        __syncthreads();
    }
    int run = boff[b] + s[t] - sum;   // exclusive offset for this thread's chunk
#pragma unroll
    for (int k = 0; k < 8; ++k) {
        int i = base + k;
        if (i < NR) { segOff[i] = run; cursor[i] = run; run += v[k]; }
    }
    if (b == 0 && t == 0) segOff[NR] = N_EDGES;
}

__global__ void scatter_kernel(const int* __restrict__ tri, int* __restrict__ cursor,
                               int* __restrict__ sortedSrc) {
    int e = blockIdx.x * 256 + threadIdx.x;
    if (e >= N_EDGES) return;
    int src = tri[3 * e];
    int rel = tri[3 * e + 1];
    int tgt = tri[3 * e + 2];
    int p = atomicAdd(&cursor[tgt * N_RELS + rel], 1);
    sortedSrc[p] = src;
}

// W[r][i][o] fp32  ->  Wt[o][r*128+i] bf16  (B-operand, K-contiguous per n-row)
__global__ void convert_w(const float* __restrict__ W, unsigned short* __restrict__ Wt) {
    int idx = blockIdx.x * 256 + threadIdx.x;
    if (idx >= N_RELS * IN_DIM * OUT_DIM) return;
    int o = idx & 127;
    int ri = idx >> 7;
    Wt[o * KDIM + ri] = f2bf(W[idx]);
}

// ---------------- fused aggregate + MFMA GEMM ----------------
// LDS agg tile: 32 nodes x 1024 K, bf16, 64 KB exactly.
// 16B chunks are rotated by node index ((chunk+node)&127) so that the
// A-fragment ds_read_b128 (16 lanes at same K, different node rows, row
// stride 2048B) hits different bank groups (2-way aliasing = free) instead
// of 16-way conflicts.
__global__ __launch_bounds__(256) void fused_kernel(
    const int* __restrict__ sortedSrc,
    const int* __restrict__ segOff,
    const float* __restrict__ features,
    const unsigned short* __restrict__ Wt,
    const float* __restrict__ bias,
    float* __restrict__ out)
{
    __shared__ unsigned short agg[NODES_PER_BLOCK * KDIM];   // 65536 B
    const int tid = threadIdx.x;
    const int wave = tid >> 6;
    const int lane = tid & 63;
    const int node0 = blockIdx.x * NODES_PER_BLOCK;

    // ---- Phase A: each wave aggregates 8 nodes; lane owns dims 2l,2l+1 ----
    for (int nl = wave * 8; nl < wave * 8 + 8; ++nl) {
        const int t = node0 + nl;
        if (t < N_NODES) {
            const int segBase = t * N_RELS;
#pragma unroll
            for (int r = 0; r < N_RELS; ++r) {
                const int s0 = segOff[segBase + r];
                const int s1 = segOff[segBase + r + 1];
                float a0 = 0.f, a1 = 0.f, b0 = 0.f, b1 = 0.f;
                int e = s0;
                for (; e + 1 < s1; e += 2) {
                    int src0 = sortedSrc[e];
                    int src1 = sortedSrc[e + 1];
                    float2 f0 = *(const float2*)&features[src0 * IN_DIM + 2 * lane];
                    float2 f1 = *(const float2*)&features[src1 * IN_DIM + 2 * lane];
                    a0 += f0.x; a1 += f0.y;
                    b0 += f1.x; b1 += f1.y;
                }
                if (e < s1) {
                    int src0 = sortedSrc[e];
                    float2 f0 = *(const float2*)&features[src0 * IN_DIM + 2 * lane];
                    a0 += f0.x; a1 += f0.y;
                }
                const int len = s1 - s0;
                const float inv = (len > 0) ? 1.0f / (float)len : 0.0f;
                a0 = (a0 + b0) * inv;
                a1 = (a1 + b1) * inv;
                const int col = r * IN_DIM + 2 * lane;
                const int chunk = col >> 3;
                const int swz = ((chunk + nl) & 127) * 8 + (col & 7);
                *(unsigned int*)&agg[nl * KDIM + swz] =
                    (unsigned)f2bf(a0) | ((unsigned)f2bf(a1) << 16);
            }
        } else {
#pragma unroll
            for (int r = 0; r < N_RELS; ++r) {
                const int col = r * IN_DIM + 2 * lane;
                const int chunk = col >> 3;
                const int swz = ((chunk + nl) & 127) * 8 + (col & 7);
                *(unsigned int*)&agg[nl * KDIM + swz] = 0u;
            }
        }
    }
    __syncthreads();

    // ---- Phase B: out[32 x 128] = agg[32 x 1024] @ Wflat[1024 x 128] ----
    // wave -> (mtile = wave&1, 4 ntiles starting at (wave>>1)*4)
    const int mt = wave & 1;
    const int ntg = wave >> 1;
    const int qk = lane >> 4;      // quad index 0..3
    const int ln16 = lane & 15;

    floatx4 acc[4];
#pragma unroll
    for (int nt = 0; nt < 4; ++nt) acc[nt] = (floatx4){0.f, 0.f, 0.f, 0.f};

    const int anode = mt * 16 + ln16;                    // local node = A-row m
    const unsigned short* aggRow = &agg[anode * KDIM];

#pragma unroll 4
    for (int ks = 0; ks < 32; ++ks) {
        const int chunk = ks * 4 + qk;
        bf16x8 a = *(const bf16x8*)&aggRow[((chunk + anode) & 127) * 8];
#pragma unroll
        for (int nt = 0; nt < 4; ++nt) {
            const int n = (ntg * 4 + nt) * 16 + ln16;
            bf16x8 b = *(const bf16x8*)&Wt[n * KDIM + ks * 32 + qk * 8];
            acc[nt] = __builtin_amdgcn_mfma_f32_16x16x32_bf16(a, b, acc[nt], 0, 0, 0);
        }
    }

    // ---- epilogue: D layout col=lane&15, row=(lane>>4)*4+reg ----
#pragma unroll
    for (int nt = 0; nt < 4; ++nt) {
        const int o = (ntg * 4 + nt) * 16 + ln16;
        const float bv = bias[o];
#pragma unroll
        for (int j = 0; j < 4; ++j) {
            const int t = node0 + mt * 16 + qk * 4 + j;
            if (t < N_NODES) out[t * OUT_DIM + o] = acc[nt][j] + bv;
        }
    }
}

extern "C" void kernel_launch(void* const* d_in, const int* in_sizes, int n_in,
                              void* d_out, int out_size, void* d_ws, size_t ws_size,
                              hipStream_t stream)
{
    const int*   tri      = (const int*)d_in[0];
    const float* features = (const float*)d_in[1];
    const float* W        = (const float*)d_in[2];
    const float* bias     = (const float*)d_in[3];
    float* out = (float*)d_out;

    char* ws = (char*)d_ws;
    unsigned short* Wt = (unsigned short*)ws; ws += (size_t)OUT_DIM * KDIM * 2;  // 256 KB, 16B-aligned
    int* cnt       = (int*)ws; ws += (size_t)NR * 4;
    int* segOff    = (int*)ws; ws += (size_t)(NR + 1) * 4;
    int* cursor    = (int*)ws; ws += (size_t)NR * 4;
    int* bsum      = (int*)ws; ws += (size_t)SCAN_NBLK * 4;
    int* boff      = (int*)ws; ws += (size_t)SCAN_NBLK * 4;
    int* sortedSrc = (int*)ws; ws += (size_t)N_EDGES * 4;
    (void)ws_size; (void)in_sizes; (void)n_in; (void)out_size;

    hipMemsetAsync(cnt, 0, NR * sizeof(int), stream);
    count_kernel<<<(N_EDGES + 255) / 256, 256, 0, stream>>>(tri, cnt);
    scan_part<<<SCAN_NBLK, 256, 0, stream>>>(cnt, bsum);
    scan_mid<<<1, 256, 0, stream>>>(bsum, boff);
    scan_apply<<<SCAN_NBLK, 256, 0, stream>>>(cnt, boff, segOff, cursor);
    convert_w<<<(N_RELS * IN_DIM * OUT_DIM + 255) / 256, 256, 0, stream>>>(W, Wt);
    scatter_kernel<<<(N_EDGES + 255) / 256, 256, 0, stream>>>(tri, cursor, sortedSrc);
    fused_kernel<<<(N_NODES + NODES_PER_BLOCK - 1) / NODES_PER_BLOCK, 256, 0, stream>>>(
        sortedSrc, segOff, features, Wt, bias, out);
}

// Round 2
// 320.230 us; speedup vs baseline: 1.6382x; 1.6382x over previous
//
#include <hip/hip_runtime.h>
#include <hip/hip_bf16.h>

#define N_NODES 50000
#define N_RELS 8
#define IN_DIM 128
#define OUT_DIM 128
#define N_EDGES 800000
#define NR (N_NODES * N_RELS)              /* 400000 keys (tgt*8+rel) */
#define KDIM (N_RELS * IN_DIM)             /* 1024 = GEMM K */
#define SCAN_ELEMS 2048
#define SCAN_NBLK ((NR + SCAN_ELEMS - 1) / SCAN_ELEMS)  /* 196 */
#define M_PAD 50048                        /* 391 blocks * 128 rows */
#define CNT_BLKS ((N_EDGES / 4 + 255) / 256)   /* 782 */
#define CW_BLKS ((N_RELS * IN_DIM * OUT_DIM + 255) / 256) /* 512 */

typedef __attribute__((ext_vector_type(8))) short bf16x8;
typedef __attribute__((ext_vector_type(4))) float floatx4;

__device__ inline unsigned short f2bf(float f) {
    unsigned u = __builtin_bit_cast(unsigned, f);
    u += 0x7fff + ((u >> 16) & 1);   // round-to-nearest-even
    return (unsigned short)(u >> 16);
}

// ---------------- sort pipeline ----------------

// blocks [0, CNT_BLKS): histogram of keys (4 edges/thread via int4 x3)
// blocks [CNT_BLKS, CNT_BLKS+CW_BLKS): W[r][i][o] fp32 -> Wt[o][r*128+i] bf16
__global__ void prep_kernel(const int* __restrict__ tri, const float* __restrict__ W,
                            int* __restrict__ cnt, unsigned short* __restrict__ Wt) {
    const int b = blockIdx.x;
    if (b < CNT_BLKS) {
        int t = b * 256 + threadIdx.x;
        if (t >= N_EDGES / 4) return;
        const int4* tri4 = (const int4*)tri;
        int4 a = tri4[3 * t], v = tri4[3 * t + 1], c = tri4[3 * t + 2];
        // edges: (a.x,a.y,a.z) (a.w,v.x,v.y) (v.z,v.w,c.x) (c.y,c.z,c.w)
        atomicAdd(&cnt[a.z * N_RELS + a.y], 1);
        atomicAdd(&cnt[v.y * N_RELS + v.x], 1);
        atomicAdd(&cnt[c.x * N_RELS + v.w], 1);
        atomicAdd(&cnt[c.w * N_RELS + c.z], 1);
    } else {
        int idx = (b - CNT_BLKS) * 256 + threadIdx.x;
        if (idx >= N_RELS * IN_DIM * OUT_DIM) return;
        int o = idx & 127;
        int ri = idx >> 7;
        Wt[o * KDIM + ri] = f2bf(W[idx]);
    }
}

__global__ void scan_part(const int* __restrict__ cnt, int* __restrict__ bsum) {
    __shared__ int s[256];
    int b = blockIdx.x, t = threadIdx.x;
    int base = b * SCAN_ELEMS + t * 8;
    int sum = 0;
#pragma unroll
    for (int k = 0; k < 8; ++k) {
        int i = base + k;
        sum += (i < NR) ? cnt[i] : 0;
    }
    s[t] = sum; __syncthreads();
    for (int off = 128; off > 0; off >>= 1) {
        if (t < off) s[t] += s[t + off];
        __syncthreads();
    }
    if (t == 0) bsum[b] = s[0];
}

__global__ void scan_mid(const int* __restrict__ bsum, int* __restrict__ boff) {
    __shared__ int s[256];
    int t = threadIdx.x;
    int v = (t < SCAN_NBLK) ? bsum[t] : 0;
    s[t] = v; __syncthreads();
    for (int off = 1; off < 256; off <<= 1) {
        int x = (t >= off) ? s[t - off] : 0;
        __syncthreads();
        s[t] += x;
        __syncthreads();
    }
    if (t < SCAN_NBLK) boff[t] = s[t] - v;   // exclusive
}

__global__ void scan_apply(const int* __restrict__ cnt, const int* __restrict__ boff,
                           int* __restrict__ segOff, int* __restrict__ cursor) {
    __shared__ int s[256];
    int b = blockIdx.x, t = threadIdx.x;
    int base = b * SCAN_ELEMS + t * 8;
    int v[8]; int sum = 0;
#pragma unroll
    for (int k = 0; k < 8; ++k) {
        int i = base + k;
        v[k] = (i < NR) ? cnt[i] : 0;
        sum += v[k];
    }
    s[t] = sum; __syncthreads();
    for (int off = 1; off < 256; off <<= 1) {
        int x = (t >= off) ? s[t - off] : 0;
        __syncthreads();
        s[t] += x;
        __syncthreads();
    }
    int run = boff[b] + s[t] - sum;   // exclusive offset for this thread's chunk
#pragma unroll
    for (int k = 0; k < 8; ++k) {
        int i = base + k;
        if (i < NR) { segOff[i] = run; cursor[i] = run; run += v[k]; }
    }
    if (b == 0 && t == 0) segOff[NR] = N_EDGES;
}

__global__ void scatter_kernel(const int* __restrict__ tri, int* __restrict__ cursor,
                               int* __restrict__ sortedSrc) {
    int t = blockIdx.x * 256 + threadIdx.x;
    if (t >= N_EDGES / 4) return;
    const int4* tri4 = (const int4*)tri;
    int4 a = tri4[3 * t], v = tri4[3 * t + 1], c = tri4[3 * t + 2];
    int p;
    p = atomicAdd(&cursor[a.z * N_RELS + a.y], 1); sortedSrc[p] = a.x;
    p = atomicAdd(&cursor[v.y * N_RELS + v.x], 1); sortedSrc[p] = a.w;
    p = atomicAdd(&cursor[c.x * N_RELS + v.w], 1); sortedSrc[p] = v.z;
    p = atomicAdd(&cursor[c.w * N_RELS + c.z], 1); sortedSrc[p] = c.y;
}

// ---------------- phase A: per-node segment mean -> bf16 agg row ----------------
// One wave per node. Lane owns dims {2*lane, 2*lane+1}. Segment bounds and the
// first 64 src indices are preloaded lane-parallel and broadcast via __shfl,
// so the only per-edge dependency left is the feature gather itself.
__global__ __launch_bounds__(256) void agg_kernel(
    const int* __restrict__ sortedSrc, const int* __restrict__ segOff,
    const float* __restrict__ features, unsigned short* __restrict__ aggG)
{
    const int wave = threadIdx.x >> 6, lane = threadIdx.x & 63;
    const int node = blockIdx.x * 4 + wave;

    int bnd = 0;
    if (lane < 9) bnd = segOff[node * N_RELS + lane];
    int s[9];
#pragma unroll
    for (int i = 0; i < 9; ++i) s[i] = __shfl(bnd, i);

    const int e0 = s[0], eN = s[8];
    int srcw = 0;
    if (e0 + lane < eN) srcw = sortedSrc[e0 + lane];   // window of 64 srcs

    unsigned short* dst = aggG + (size_t)node * KDIM + 2 * lane;
    const float* fbase = features + 2 * lane;

#pragma unroll
    for (int r = 0; r < N_RELS; ++r) {
        const int s0 = s[r], s1 = s[r + 1];
        float a0 = 0.f, a1 = 0.f, b0 = 0.f, b1 = 0.f;
        int e = s0;
        for (; e + 1 < s1; e += 2) {
            int i0 = e - e0;
            int src0 = (i0 < 64) ? __shfl(srcw, i0) : sortedSrc[e];
            int src1 = (i0 + 1 < 64) ? __shfl(srcw, i0 + 1) : sortedSrc[e + 1];
            float2 f0 = *(const float2*)&fbase[src0 * IN_DIM];
            float2 f1 = *(const float2*)&fbase[src1 * IN_DIM];
            a0 += f0.x; a1 += f0.y;
            b0 += f1.x; b1 += f1.y;
        }
        if (e < s1) {
            int i0 = e - e0;
            int src0 = (i0 < 64) ? __shfl(srcw, i0) : sortedSrc[e];
            float2 f0 = *(const float2*)&fbase[src0 * IN_DIM];
            a0 += f0.x; a1 += f0.y;
        }
        const float inv = (s1 > s0) ? 1.0f / (float)(s1 - s0) : 0.0f;
        a0 = (a0 + b0) * inv;
        a1 = (a1 + b1) * inv;
        *(unsigned*)&dst[r * IN_DIM] = (unsigned)f2bf(a0) | ((unsigned)f2bf(a1) << 16);
    }
}

// ---------------- phase B: out[M_PAD x 128] = agg @ Wt^T + bias ----------------
// No LDS: A gathered straight from global (each element read once, reused 8x
// in regs across N-tiles); B (256 KB) stays L2-resident. 32 rows per wave.
__global__ __launch_bounds__(256) void gemm_kernel(
    const unsigned short* __restrict__ aggG,
    const unsigned short* __restrict__ Wt,
    const float* __restrict__ bias,
    float* __restrict__ out)
{
    const int wave = threadIdx.x >> 6, lane = threadIdx.x & 63;
    const int qk = lane >> 4, ln16 = lane & 15;
    const int m0 = blockIdx.x * 128 + wave * 32;

    floatx4 acc[2][8];
#pragma unroll
    for (int mt = 0; mt < 2; ++mt)
#pragma unroll
        for (int nt = 0; nt < 8; ++nt) acc[mt][nt] = (floatx4){0.f, 0.f, 0.f, 0.f};

    const unsigned short* aRow0 = aggG + (size_t)(m0 + ln16) * KDIM + qk * 8;
    const unsigned short* aRow1 = aRow0 + 16 * KDIM;
    const unsigned short* bBase = Wt + (size_t)ln16 * KDIM + qk * 8;

#pragma unroll 4
    for (int ks = 0; ks < 32; ++ks) {
        bf16x8 a0 = *(const bf16x8*)&aRow0[ks * 32];
        bf16x8 a1 = *(const bf16x8*)&aRow1[ks * 32];
#pragma unroll
        for (int nt = 0; nt < 8; ++nt) {
            bf16x8 b = *(const bf16x8*)&bBase[nt * 16 * KDIM + ks * 32];
            acc[0][nt] = __builtin_amdgcn_mfma_f32_16x16x32_bf16(a0, b, acc[0][nt], 0, 0, 0);
            acc[1][nt] = __builtin_amdgcn_mfma_f32_16x16x32_bf16(a1, b, acc[1][nt], 0, 0, 0);
        }
    }

    // D layout: col = lane&15, row = (lane>>4)*4 + reg
#pragma unroll
    for (int nt = 0; nt < 8; ++nt) {
        const int o = nt * 16 + ln16;
        const float bv = bias[o];
#pragma unroll
        for (int mt = 0; mt < 2; ++mt)
#pragma unroll
            for (int j = 0; j < 4; ++j) {
                const int t = m0 + mt * 16 + qk * 4 + j;
                if (t < N_NODES) out[(size_t)t * OUT_DIM + o] = acc[mt][nt][j] + bv;
            }
    }
}

// ---------------- fallback: round-1 fused kernel (small-ws path) ----------------
#define NODES_PER_BLOCK 32
__global__ __launch_bounds__(256) void fused_kernel(
    const int* __restrict__ sortedSrc,
    const int* __restrict__ segOff,
    const float* __restrict__ features,
    const unsigned short* __restrict__ Wt,
    const float* __restrict__ bias,
    float* __restrict__ out)
{
    __shared__ unsigned short agg[NODES_PER_BLOCK * KDIM];
    const int tid = threadIdx.x;
    const int wave = tid >> 6;
    const int lane = tid & 63;
    const int node0 = blockIdx.x * NODES_PER_BLOCK;

    for (int nl = wave * 8; nl < wave * 8 + 8; ++nl) {
        const int t = node0 + nl;
        if (t < N_NODES) {
            const int segBase = t * N_RELS;
#pragma unroll
            for (int r = 0; r < N_RELS; ++r) {
                const int s0 = segOff[segBase + r];
                const int s1 = segOff[segBase + r + 1];
                float a0 = 0.f, a1 = 0.f, b0 = 0.f, b1 = 0.f;
                int e = s0;
                for (; e + 1 < s1; e += 2) {
                    int src0 = sortedSrc[e];
                    int src1 = sortedSrc[e + 1];
                    float2 f0 = *(const float2*)&features[src0 * IN_DIM + 2 * lane];
                    float2 f1 = *(const float2*)&features[src1 * IN_DIM + 2 * lane];
                    a0 += f0.x; a1 += f0.y;
                    b0 += f1.x; b1 += f1.y;
                }
                if (e < s1) {
                    int src0 = sortedSrc[e];
                    float2 f0 = *(const float2*)&features[src0 * IN_DIM + 2 * lane];
                    a0 += f0.x; a1 += f0.y;
                }
                const int len = s1 - s0;
                const float inv = (len > 0) ? 1.0f / (float)len : 0.0f;
                a0 = (a0 + b0) * inv;
                a1 = (a1 + b1) * inv;
                const int col = r * IN_DIM + 2 * lane;
                const int chunk = col >> 3;
                const int swz = ((chunk + nl) & 127) * 8 + (col & 7);
                *(unsigned int*)&agg[nl * KDIM + swz] =
                    (unsigned)f2bf(a0) | ((unsigned)f2bf(a1) << 16);
            }
        } else {
#pragma unroll
            for (int r = 0; r < N_RELS; ++r) {
                const int col = r * IN_DIM + 2 * lane;
                const int chunk = col >> 3;
                const int swz = ((chunk + nl) & 127) * 8 + (col & 7);
                *(unsigned int*)&agg[nl * KDIM + swz] = 0u;
            }
        }
    }
    __syncthreads();

    const int mt = wave & 1;
    const int ntg = wave >> 1;
    const int qk = lane >> 4;
    const int ln16 = lane & 15;

    floatx4 acc[4];
#pragma unroll
    for (int nt = 0; nt < 4; ++nt) acc[nt] = (floatx4){0.f, 0.f, 0.f, 0.f};

    const int anode = mt * 16 + ln16;
    const unsigned short* aggRow = &agg[anode * KDIM];

#pragma unroll 4
    for (int ks = 0; ks < 32; ++ks) {
        const int chunk = ks * 4 + qk;
        bf16x8 a = *(const bf16x8*)&aggRow[((chunk + anode) & 127) * 8];
#pragma unroll
        for (int nt = 0; nt < 4; ++nt) {
            const int n = (ntg * 4 + nt) * 16 + ln16;
            bf16x8 b = *(const bf16x8*)&Wt[n * KDIM + ks * 32 + qk * 8];
            acc[nt] = __builtin_amdgcn_mfma_f32_16x16x32_bf16(a, b, acc[nt], 0, 0, 0);
        }
    }

#pragma unroll
    for (int nt = 0; nt < 4; ++nt) {
        const int o = (ntg * 4 + nt) * 16 + ln16;
        const float bv = bias[o];
#pragma unroll
        for (int j = 0; j < 4; ++j) {
            const int t = node0 + mt * 16 + qk * 4 + j;
            if (t < N_NODES) out[t * OUT_DIM + o] = acc[nt][j] + bv;
        }
    }
}

extern "C" void kernel_launch(void* const* d_in, const int* in_sizes, int n_in,
                              void* d_out, int out_size, void* d_ws, size_t ws_size,
                              hipStream_t stream)
{
    const int*   tri      = (const int*)d_in[0];
    const float* features = (const float*)d_in[1];
    const float* W        = (const float*)d_in[2];
    const float* bias     = (const float*)d_in[3];
    float* out = (float*)d_out;

    char* ws = (char*)d_ws;
    unsigned short* Wt = (unsigned short*)ws; ws += (size_t)OUT_DIM * KDIM * 2;  // 256 KB
    int* cnt       = (int*)ws; ws += (size_t)NR * 4;
    int* segOff    = (int*)ws; ws += (size_t)(NR + 1) * 4;
    int* cursor    = (int*)ws; ws += (size_t)NR * 4;
    int* bsum      = (int*)ws; ws += (size_t)SCAN_NBLK * 4;
    int* boff      = (int*)ws; ws += (size_t)SCAN_NBLK * 4;
    int* sortedSrc = (int*)ws; ws += (size_t)N_EDGES * 4;
    unsigned short* aggG = (unsigned short*)ws; ws += (size_t)M_PAD * KDIM * 2;  // 102.5 MB
    const size_t need = (size_t)(ws - (char*)d_ws);
    (void)in_sizes; (void)n_in; (void)out_size;

    hipMemsetAsync(cnt, 0, NR * sizeof(int), stream);
    prep_kernel<<<CNT_BLKS + CW_BLKS, 256, 0, stream>>>(tri, W, cnt, Wt);
    scan_part<<<SCAN_NBLK, 256, 0, stream>>>(cnt, bsum);
    scan_mid<<<1, 256, 0, stream>>>(bsum, boff);
    scan_apply<<<SCAN_NBLK, 256, 0, stream>>>(cnt, boff, segOff, cursor);
    scatter_kernel<<<CNT_BLKS, 256, 0, stream>>>(tri, cursor, sortedSrc);

    if (ws_size >= need) {
        agg_kernel<<<N_NODES / 4, 256, 0, stream>>>(sortedSrc, segOff, features, aggG);
        gemm_kernel<<<M_PAD / 128, 256, 0, stream>>>(aggG, Wt, bias, out);
    } else {
        fused_kernel<<<(N_NODES + NODES_PER_BLOCK - 1) / NODES_PER_BLOCK, 256, 0, stream>>>(
            sortedSrc, segOff, features, Wt, bias, out);
    }
}

// Round 3
// 281.246 us; speedup vs baseline: 1.8653x; 1.1386x over previous
//
#include <hip/hip_runtime.h>
#include <hip/hip_bf16.h>

#define N_NODES 50000
#define N_RELS 8
#define IN_DIM 128
#define OUT_DIM 128
#define N_EDGES 800000
#define NR (N_NODES * N_RELS)              /* 400000 keys (tgt*8+rel) */
#define KDIM (N_RELS * IN_DIM)             /* 1024 = GEMM K */
#define SCAN_ELEMS 2048
#define SCAN_NBLK ((NR + SCAN_ELEMS - 1) / SCAN_ELEMS)  /* 196 */
#define M_PAD 50048                        /* 782 blocks * 64 rows */
#define CNT_BLKS ((N_EDGES / 4 + 255) / 256)   /* 782 */
#define CW_BLKS ((N_RELS * IN_DIM * OUT_DIM + 255) / 256) /* 512 */

typedef __attribute__((ext_vector_type(8))) short bf16x8;
typedef __attribute__((ext_vector_type(4))) float floatx4;

__device__ inline unsigned short f2bf(float f) {
    unsigned u = __builtin_bit_cast(unsigned, f);
    u += 0x7fff + ((u >> 16) & 1);   // round-to-nearest-even
    return (unsigned short)(u >> 16);
}

// ---------------- sort pipeline ----------------

// blocks [0, CNT_BLKS): histogram of keys (4 edges/thread via int4 x3)
// blocks [CNT_BLKS, ...): W[r][i][o] fp32 -> fragment-major bf16 Wtf.
// Wtf[((nt*32+ks)*64+lane)*8+e] = W-element for B-frag (n = nt*16+(lane&15),
// k = ks*32+(lane>>4)*8+e) so each B-fragment load in the GEMM is one
// contiguous 1 KB wave read.
__global__ void prep_kernel(const int* __restrict__ tri, const float* __restrict__ W,
                            int* __restrict__ cnt, unsigned short* __restrict__ Wtf) {
    const int b = blockIdx.x;
    if (b < CNT_BLKS) {
        int t = b * 256 + threadIdx.x;
        if (t >= N_EDGES / 4) return;
        const int4* tri4 = (const int4*)tri;
        int4 a = tri4[3 * t], v = tri4[3 * t + 1], c = tri4[3 * t + 2];
        // edges: (a.x,a.y,a.z) (a.w,v.x,v.y) (v.z,v.w,c.x) (c.y,c.z,c.w)
        atomicAdd(&cnt[a.z * N_RELS + a.y], 1);
        atomicAdd(&cnt[v.y * N_RELS + v.x], 1);
        atomicAdd(&cnt[c.x * N_RELS + v.w], 1);
        atomicAdd(&cnt[c.w * N_RELS + c.z], 1);
    } else {
        int idx = (b - CNT_BLKS) * 256 + threadIdx.x;   // 0 .. 131071
        if (idx >= N_RELS * IN_DIM * OUT_DIM) return;
        int e  = idx & 7;
        int l  = (idx >> 3) & 63;
        int ks = (idx >> 9) & 31;
        int nt = idx >> 14;
        int o = nt * 16 + (l & 15);
        int k = ks * 32 + (l >> 4) * 8 + e;             // global K index
        Wtf[idx] = f2bf(W[(k >> 7) * (IN_DIM * OUT_DIM) + (k & 127) * OUT_DIM + o]);
    }
}

__global__ void scan_part(const int* __restrict__ cnt, int* __restrict__ bsum) {
    __shared__ int s[256];
    int b = blockIdx.x, t = threadIdx.x;
    int base = b * SCAN_ELEMS + t * 8;
    int sum = 0;
#pragma unroll
    for (int k = 0; k < 8; ++k) {
        int i = base + k;
        sum += (i < NR) ? cnt[i] : 0;
    }
    s[t] = sum; __syncthreads();
    for (int off = 128; off > 0; off >>= 1) {
        if (t < off) s[t] += s[t + off];
        __syncthreads();
    }
    if (t == 0) bsum[b] = s[0];
}

__global__ void scan_mid(const int* __restrict__ bsum, int* __restrict__ boff) {
    __shared__ int s[256];
    int t = threadIdx.x;
    int v = (t < SCAN_NBLK) ? bsum[t] : 0;
    s[t] = v; __syncthreads();
    for (int off = 1; off < 256; off <<= 1) {
        int x = (t >= off) ? s[t - off] : 0;
        __syncthreads();
        s[t] += x;
        __syncthreads();
    }
    if (t < SCAN_NBLK) boff[t] = s[t] - v;   // exclusive
}

__global__ void scan_apply(const int* __restrict__ cnt, const int* __restrict__ boff,
                           int* __restrict__ segOff, int* __restrict__ cursor) {
    __shared__ int s[256];
    int b = blockIdx.x, t = threadIdx.x;
    int base = b * SCAN_ELEMS + t * 8;
    int v[8]; int sum = 0;
#pragma unroll
    for (int k = 0; k < 8; ++k) {
        int i = base + k;
        v[k] = (i < NR) ? cnt[i] : 0;
        sum += v[k];
    }
    s[t] = sum; __syncthreads();
    for (int off = 1; off < 256; off <<= 1) {
        int x = (t >= off) ? s[t - off] : 0;
        __syncthreads();
        s[t] += x;
        __syncthreads();
    }
    int run = boff[b] + s[t] - sum;   // exclusive offset for this thread's chunk
#pragma unroll
    for (int k = 0; k < 8; ++k) {
        int i = base + k;
        if (i < NR) { segOff[i] = run; cursor[i] = run; run += v[k]; }
    }
    if (b == 0 && t == 0) segOff[NR] = N_EDGES;
}

__global__ void scatter_kernel(const int* __restrict__ tri, int* __restrict__ cursor,
                               int* __restrict__ sortedSrc) {
    int t = blockIdx.x * 256 + threadIdx.x;
    if (t >= N_EDGES / 4) return;
    const int4* tri4 = (const int4*)tri;
    int4 a = tri4[3 * t], v = tri4[3 * t + 1], c = tri4[3 * t + 2];
    int p;
    p = atomicAdd(&cursor[a.z * N_RELS + a.y], 1); sortedSrc[p] = a.x;
    p = atomicAdd(&cursor[v.y * N_RELS + v.x], 1); sortedSrc[p] = a.w;
    p = atomicAdd(&cursor[c.x * N_RELS + v.w], 1); sortedSrc[p] = v.z;
    p = atomicAdd(&cursor[c.w * N_RELS + c.z], 1); sortedSrc[p] = c.y;
}

// ---------------- phase A: per-node segment mean -> bf16 agg row ----------------
// One wave per node. Lane owns dims {2*lane, 2*lane+1}. Segment bounds and the
// first 64 src indices preloaded lane-parallel and broadcast via __shfl.
__global__ __launch_bounds__(256) void agg_kernel(
    const int* __restrict__ sortedSrc, const int* __restrict__ segOff,
    const float* __restrict__ features, unsigned short* __restrict__ aggG)
{
    const int wave = threadIdx.x >> 6, lane = threadIdx.x & 63;
    const int node = blockIdx.x * 4 + wave;

    int bnd = 0;
    if (lane < 9) bnd = segOff[node * N_RELS + lane];
    int s[9];
#pragma unroll
    for (int i = 0; i < 9; ++i) s[i] = __shfl(bnd, i);

    const int e0 = s[0], eN = s[8];
    int srcw = 0;
    if (e0 + lane < eN) srcw = sortedSrc[e0 + lane];   // window of 64 srcs

    unsigned short* dst = aggG + (size_t)node * KDIM + 2 * lane;
    const float* fbase = features + 2 * lane;

#pragma unroll
    for (int r = 0; r < N_RELS; ++r) {
        const int s0 = s[r], s1 = s[r + 1];
        float a0 = 0.f, a1 = 0.f, b0 = 0.f, b1 = 0.f;
        int e = s0;
        for (; e + 1 < s1; e += 2) {
            int i0 = e - e0;
            int src0 = (i0 < 64) ? __shfl(srcw, i0) : sortedSrc[e];
            int src1 = (i0 + 1 < 64) ? __shfl(srcw, i0 + 1) : sortedSrc[e + 1];
            float2 f0 = *(const float2*)&fbase[src0 * IN_DIM];
            float2 f1 = *(const float2*)&fbase[src1 * IN_DIM];
            a0 += f0.x; a1 += f0.y;
            b0 += f1.x; b1 += f1.y;
        }
        if (e < s1) {
            int i0 = e - e0;
            int src0 = (i0 < 64) ? __shfl(srcw, i0) : sortedSrc[e];
            float2 f0 = *(const float2*)&fbase[src0 * IN_DIM];
            a0 += f0.x; a1 += f0.y;
        }
        const float inv = (s1 > s0) ? 1.0f / (float)(s1 - s0) : 0.0f;
        a0 = (a0 + b0) * inv;
        a1 = (a1 + b1) * inv;
        *(unsigned*)&dst[r * IN_DIM] = (unsigned)f2bf(a0) | ((unsigned)f2bf(a1) << 16);
    }
}

// ---------------- phase B: out[M_PAD x 128] = agg @ W + bias ----------------
// Block = 64 rows x 128 cols, 4 waves, wave-tile 32x64. A staged to LDS via
// global_load_lds (16 B) with XOR-16 swizzle: LDS[row][u] = global[row][u^(row&15)]
//  - staging reads: 16 contiguous lanes cover one full 256 B row segment
//  - A-frag ds_read_b128: 16 lanes hit perm(0..15) 16B units -> 2-way = free
// B-frags are contiguous 1 KB loads from fragment-major Wtf (L2-resident).
__global__ __launch_bounds__(256) void gemm_kernel(
    const unsigned short* __restrict__ aggG,
    const unsigned short* __restrict__ Wtf,
    const float* __restrict__ bias,
    float* __restrict__ out)
{
    __shared__ unsigned short Abuf[64 * 128];   // 16 KB, row stride 256 B
    const int tid = threadIdx.x;
    const int wave = tid >> 6, lane = tid & 63;
    const int qk = lane >> 4, ln16 = lane & 15;
    const int m0 = blockIdx.x * 64;
    const int wm = wave & 1, wn = wave >> 1;

    floatx4 acc[2][4];
#pragma unroll
    for (int st = 0; st < 2; ++st)
#pragma unroll
        for (int nt = 0; nt < 4; ++nt) acc[st][nt] = (floatx4){0.f, 0.f, 0.f, 0.f};

    const int l4 = lane >> 4, l15 = lane & 15;

    for (int c = 0; c < 8; ++c) {
        __syncthreads();                 // previous chunk fully consumed
#pragma unroll
        for (int i = 0; i < 4; ++i) {
            const int row = wave * 16 + i * 4 + l4;          // 0..63
            const int unit = l15 ^ (row & 15);
            const unsigned short* g =
                aggG + (size_t)(m0 + row) * KDIM + c * 128 + unit * 8;
            __builtin_amdgcn_global_load_lds(
                (const __attribute__((address_space(1))) unsigned int*)g,
                (__attribute__((address_space(3))) unsigned int*)&Abuf[(wave * 16 + i * 4) * 128],
                16, 0, 0);
        }
        __syncthreads();                 // staging visible (vmcnt drained)

#pragma unroll
        for (int ksl = 0; ksl < 4; ++ksl) {
            const int ks = c * 4 + ksl;
            bf16x8 a[2];
#pragma unroll
            for (int st = 0; st < 2; ++st) {
                const int r = wm * 32 + st * 16 + ln16;
                const int u = (ksl * 4 + qk) ^ (r & 15);
                a[st] = *(const bf16x8*)&Abuf[r * 128 + u * 8];
            }
#pragma unroll
            for (int nt = 0; nt < 4; ++nt) {
                const int ntg = wn * 4 + nt;
                bf16x8 b = *(const bf16x8*)&Wtf[(size_t)((ntg * 32 + ks) * 64 + lane) * 8];
                acc[0][nt] = __builtin_amdgcn_mfma_f32_16x16x32_bf16(a[0], b, acc[0][nt], 0, 0, 0);
                acc[1][nt] = __builtin_amdgcn_mfma_f32_16x16x32_bf16(a[1], b, acc[1][nt], 0, 0, 0);
            }
        }
    }

    // D layout: col = lane&15, row = (lane>>4)*4 + reg
#pragma unroll
    for (int nt = 0; nt < 4; ++nt) {
        const int o = (wn * 4 + nt) * 16 + ln16;
        const float bv = bias[o];
#pragma unroll
        for (int st = 0; st < 2; ++st)
#pragma unroll
            for (int j = 0; j < 4; ++j) {
                const int t = m0 + wm * 32 + st * 16 + qk * 4 + j;
                if (t < N_NODES) out[(size_t)t * OUT_DIM + o] = acc[st][nt][j] + bv;
            }
    }
}

extern "C" void kernel_launch(void* const* d_in, const int* in_sizes, int n_in,
                              void* d_out, int out_size, void* d_ws, size_t ws_size,
                              hipStream_t stream)
{
    const int*   tri      = (const int*)d_in[0];
    const float* features = (const float*)d_in[1];
    const float* W        = (const float*)d_in[2];
    const float* bias     = (const float*)d_in[3];
    float* out = (float*)d_out;

    char* ws = (char*)d_ws;
    unsigned short* Wtf = (unsigned short*)ws; ws += (size_t)OUT_DIM * KDIM * 2;  // 256 KB
    int* cnt       = (int*)ws; ws += (size_t)NR * 4;
    int* segOff    = (int*)ws; ws += (size_t)(NR + 1) * 4;
    int* cursor    = (int*)ws; ws += (size_t)NR * 4;
    int* bsum      = (int*)ws; ws += (size_t)SCAN_NBLK * 4;
    int* boff      = (int*)ws; ws += (size_t)SCAN_NBLK * 4;
    int* sortedSrc = (int*)ws; ws += (size_t)N_EDGES * 4;
    unsigned short* aggG = (unsigned short*)ws; ws += (size_t)M_PAD * KDIM * 2;  // 102.5 MB
    (void)ws_size; (void)in_sizes; (void)n_in; (void)out_size;

    hipMemsetAsync(cnt, 0, NR * sizeof(int), stream);
    prep_kernel<<<CNT_BLKS + CW_BLKS, 256, 0, stream>>>(tri, W, cnt, Wtf);
    scan_part<<<SCAN_NBLK, 256, 0, stream>>>(cnt, bsum);
    scan_mid<<<1, 256, 0, stream>>>(bsum, boff);
    scan_apply<<<SCAN_NBLK, 256, 0, stream>>>(cnt, boff, segOff, cursor);
    scatter_kernel<<<CNT_BLKS, 256, 0, stream>>>(tri, cursor, sortedSrc);
    agg_kernel<<<N_NODES / 4, 256, 0, stream>>>(sortedSrc, segOff, features, aggG);
    gemm_kernel<<<M_PAD / 64, 256, 0, stream>>>(aggG, Wtf, bias, out);
}

// Round 4
// 278.832 us; speedup vs baseline: 1.8814x; 1.0087x over previous
//
#include <hip/hip_runtime.h>
#include <hip/hip_bf16.h>

#define N_NODES 50000
#define N_RELS 8
#define IN_DIM 128
#define OUT_DIM 128
#define N_EDGES 800000
#define NR (N_NODES * N_RELS)              /* 400000 keys (tgt*8+rel) */
#define KDIM (N_RELS * IN_DIM)             /* 1024 = GEMM K */
#define SCAN_ELEMS 2048
#define SCAN_NBLK ((NR + SCAN_ELEMS - 1) / SCAN_ELEMS)  /* 196 */
#define M_PAD 50048                        /* 782 blocks * 64 rows */
#define CNT_BLKS ((N_EDGES / 4 + 255) / 256)   /* 782 */
#define CW_BLKS ((N_RELS * IN_DIM * OUT_DIM + 255) / 256) /* 512 */
#define FB_BLKS ((N_NODES * IN_DIM / 8 + 255) / 256)      /* 3125 */

typedef __attribute__((ext_vector_type(8))) short bf16x8;
typedef __attribute__((ext_vector_type(4))) float floatx4;

__device__ inline unsigned short f2bf(float f) {
    unsigned u = __builtin_bit_cast(unsigned, f);
    u += 0x7fff + ((u >> 16) & 1);   // round-to-nearest-even
    return (unsigned short)(u >> 16);
}
__device__ inline float bflo(unsigned u) {   // low bf16 of a packed pair
    return __builtin_bit_cast(float, u << 16);
}
__device__ inline float bfhi(unsigned u) {   // high bf16 of a packed pair
    return __builtin_bit_cast(float, u & 0xffff0000u);
}

// ---------------- prep: histogram + W-conversion + feature-conversion ----------------
// blocks [0, CNT_BLKS): histogram of keys (4 edges/thread via int4 x3)
// blocks [CNT_BLKS, +CW_BLKS): W[r][i][o] fp32 -> fragment-major bf16 Wtf:
//   Wtf[((nt*32+ks)*64+lane)*8+e] = W for B-frag (n=nt*16+(lane&15), k=ks*32+(lane>>4)*8+e)
//   so each B-fragment load in the GEMM is one contiguous 1 KB wave read.
// blocks [CNT_BLKS+CW_BLKS, +FB_BLKS): features fp32 -> bf16 featB (row = 256 B)
__global__ void prep_kernel(const int* __restrict__ tri, const float* __restrict__ W,
                            const float* __restrict__ features,
                            int* __restrict__ cnt, unsigned short* __restrict__ Wtf,
                            unsigned short* __restrict__ featB) {
    const int b = blockIdx.x;
    if (b < CNT_BLKS) {
        int t = b * 256 + threadIdx.x;
        if (t >= N_EDGES / 4) return;
        const int4* tri4 = (const int4*)tri;
        int4 a = tri4[3 * t], v = tri4[3 * t + 1], c = tri4[3 * t + 2];
        // edges: (a.x,a.y,a.z) (a.w,v.x,v.y) (v.z,v.w,c.x) (c.y,c.z,c.w)
        atomicAdd(&cnt[a.z * N_RELS + a.y], 1);
        atomicAdd(&cnt[v.y * N_RELS + v.x], 1);
        atomicAdd(&cnt[c.x * N_RELS + v.w], 1);
        atomicAdd(&cnt[c.w * N_RELS + c.z], 1);
    } else if (b < CNT_BLKS + CW_BLKS) {
        int idx = (b - CNT_BLKS) * 256 + threadIdx.x;   // 0 .. 131071
        if (idx >= N_RELS * IN_DIM * OUT_DIM) return;
        int e  = idx & 7;
        int l  = (idx >> 3) & 63;
        int ks = (idx >> 9) & 31;
        int nt = idx >> 14;
        int o = nt * 16 + (l & 15);
        int k = ks * 32 + (l >> 4) * 8 + e;             // global K index
        Wtf[idx] = f2bf(W[(k >> 7) * (IN_DIM * OUT_DIM) + (k & 127) * OUT_DIM + o]);
    } else {
        int t = (b - CNT_BLKS - CW_BLKS) * 256 + threadIdx.x;   // 8 floats each
        if (t >= N_NODES * IN_DIM / 8) return;
        const float4* f4 = (const float4*)features;
        float4 x = f4[2 * t], y = f4[2 * t + 1];
        uint4 o;
        o.x = (unsigned)f2bf(x.x) | ((unsigned)f2bf(x.y) << 16);
        o.y = (unsigned)f2bf(x.z) | ((unsigned)f2bf(x.w) << 16);
        o.z = (unsigned)f2bf(y.x) | ((unsigned)f2bf(y.y) << 16);
        o.w = (unsigned)f2bf(y.z) | ((unsigned)f2bf(y.w) << 16);
        ((uint4*)featB)[t] = o;
    }
}

__global__ void scan_part(const int* __restrict__ cnt, int* __restrict__ bsum) {
    __shared__ int s[256];
    int b = blockIdx.x, t = threadIdx.x;
    int base = b * SCAN_ELEMS + t * 8;
    int sum = 0;
#pragma unroll
    for (int k = 0; k < 8; ++k) {
        int i = base + k;
        sum += (i < NR) ? cnt[i] : 0;
    }
    s[t] = sum; __syncthreads();
    for (int off = 128; off > 0; off >>= 1) {
        if (t < off) s[t] += s[t + off];
        __syncthreads();
    }
    if (t == 0) bsum[b] = s[0];
}

__global__ void scan_mid(const int* __restrict__ bsum, int* __restrict__ boff) {
    __shared__ int s[256];
    int t = threadIdx.x;
    int v = (t < SCAN_NBLK) ? bsum[t] : 0;
    s[t] = v; __syncthreads();
    for (int off = 1; off < 256; off <<= 1) {
        int x = (t >= off) ? s[t - off] : 0;
        __syncthreads();
        s[t] += x;
        __syncthreads();
    }
    if (t < SCAN_NBLK) boff[t] = s[t] - v;   // exclusive
}

__global__ void scan_apply(const int* __restrict__ cnt, const int* __restrict__ boff,
                           int* __restrict__ segOff, int* __restrict__ cursor) {
    __shared__ int s[256];
    int b = blockIdx.x, t = threadIdx.x;
    int base = b * SCAN_ELEMS + t * 8;
    int v[8]; int sum = 0;
#pragma unroll
    for (int k = 0; k < 8; ++k) {
        int i = base + k;
        v[k] = (i < NR) ? cnt[i] : 0;
        sum += v[k];
    }
    s[t] = sum; __syncthreads();
    for (int off = 1; off < 256; off <<= 1) {
        int x = (t >= off) ? s[t - off] : 0;
        __syncthreads();
        s[t] += x;
        __syncthreads();
    }
    int run = boff[b] + s[t] - sum;   // exclusive offset for this thread's chunk
#pragma unroll
    for (int k = 0; k < 8; ++k) {
        int i = base + k;
        if (i < NR) { segOff[i] = run; cursor[i] = run; run += v[k]; }
    }
    if (b == 0 && t == 0) segOff[NR] = N_EDGES;
}

__global__ void scatter_kernel(const int* __restrict__ tri, int* __restrict__ cursor,
                               int* __restrict__ sortedSrc) {
    int t = blockIdx.x * 256 + threadIdx.x;
    if (t >= N_EDGES / 4) return;
    const int4* tri4 = (const int4*)tri;
    int4 a = tri4[3 * t], v = tri4[3 * t + 1], c = tri4[3 * t + 2];
    int p;
    p = atomicAdd(&cursor[a.z * N_RELS + a.y], 1); sortedSrc[p] = a.x;
    p = atomicAdd(&cursor[v.y * N_RELS + v.x], 1); sortedSrc[p] = a.w;
    p = atomicAdd(&cursor[c.x * N_RELS + v.w], 1); sortedSrc[p] = v.z;
    p = atomicAdd(&cursor[c.w * N_RELS + c.z], 1); sortedSrc[p] = c.y;
}

// ---------------- phase A: per-node segment mean -> bf16 agg row ----------------
// One wave per node, bf16 gathers. A bf16 row is 256 B = 32 lanes x 8 B, so
// lanes 0-31 process edge e, lanes 32-63 edge e+1 (lane owns dims 4l..4l+3);
// one __shfl_xor(...,32) per segment merges the halves. Per 2-edge iteration:
// one 8 B load per lane (was two in fp32), halving gather bytes + load count.
__global__ __launch_bounds__(256) void agg_kernel(
    const int* __restrict__ sortedSrc, const int* __restrict__ segOff,
    const unsigned short* __restrict__ featB, unsigned short* __restrict__ aggG)
{
    const int wave = threadIdx.x >> 6, lane = threadIdx.x & 63;
    const int node = blockIdx.x * 4 + wave;
    const int h = lane >> 5, l = lane & 31;

    int bnd = 0;
    if (lane < 9) bnd = segOff[node * N_RELS + lane];
    int s[9];
#pragma unroll
    for (int i = 0; i < 9; ++i) s[i] = __shfl(bnd, i);

    const int e0 = s[0], eN = s[8];
    int srcw = 0;
    if (e0 + lane < eN) srcw = sortedSrc[e0 + lane];   // window of 64 srcs

    const unsigned short* fb = featB + 4 * l;          // dims 4l..4l+3
    unsigned short* dst = aggG + (size_t)node * KDIM + 4 * l;

#pragma unroll
    for (int r = 0; r < N_RELS; ++r) {
        const int s0 = s[r], s1 = s[r + 1];
        float a0 = 0.f, a1 = 0.f, a2 = 0.f, a3 = 0.f;
        for (int e = s0 + h; e < s1; e += 2) {
            const int i0 = e - e0;
            const int src = (i0 < 64) ? __shfl(srcw, i0) : sortedSrc[e];
            uint2 u = *(const uint2*)&fb[src * IN_DIM];
            a0 += bflo(u.x); a1 += bfhi(u.x);
            a2 += bflo(u.y); a3 += bfhi(u.y);
        }
        a0 += __shfl_xor(a0, 32);
        a1 += __shfl_xor(a1, 32);
        a2 += __shfl_xor(a2, 32);
        a3 += __shfl_xor(a3, 32);
        const float inv = (s1 > s0) ? 1.0f / (float)(s1 - s0) : 0.0f;
        if (h == 0) {
            uint2 p;
            p.x = (unsigned)f2bf(a0 * inv) | ((unsigned)f2bf(a1 * inv) << 16);
            p.y = (unsigned)f2bf(a2 * inv) | ((unsigned)f2bf(a3 * inv) << 16);
            *(uint2*)&dst[r * IN_DIM] = p;
        }
    }
}

// ---------------- phase B: out[M_PAD x 128] = agg @ W + bias ----------------
// Block = 64 rows x 128 cols, 4 waves, wave-tile 32x64. A staged to LDS via
// global_load_lds (16 B) with XOR-16 swizzle: LDS[row][u] = global[row][u^(row&15)]
//  - staging reads: 16 contiguous lanes cover one full 256 B row segment
//  - A-frag ds_read_b128: 16 lanes hit perm(0..15) 16B units -> 2-way = free
// B-frags are contiguous 1 KB loads from fragment-major Wtf (L2-resident).
__global__ __launch_bounds__(256) void gemm_kernel(
    const unsigned short* __restrict__ aggG,
    const unsigned short* __restrict__ Wtf,
    const float* __restrict__ bias,
    float* __restrict__ out)
{
    __shared__ unsigned short Abuf[64 * 128];   // 16 KB, row stride 256 B
    const int tid = threadIdx.x;
    const int wave = tid >> 6, lane = tid & 63;
    const int qk = lane >> 4, ln16 = lane & 15;
    const int m0 = blockIdx.x * 64;
    const int wm = wave & 1, wn = wave >> 1;

    floatx4 acc[2][4];
#pragma unroll
    for (int st = 0; st < 2; ++st)
#pragma unroll
        for (int nt = 0; nt < 4; ++nt) acc[st][nt] = (floatx4){0.f, 0.f, 0.f, 0.f};

    const int l4 = lane >> 4, l15 = lane & 15;

    for (int c = 0; c < 8; ++c) {
        __syncthreads();                 // previous chunk fully consumed
#pragma unroll
        for (int i = 0; i < 4; ++i) {
            const int row = wave * 16 + i * 4 + l4;          // 0..63
            const int unit = l15 ^ (row & 15);
            const unsigned short* g =
                aggG + (size_t)(m0 + row) * KDIM + c * 128 + unit * 8;
            __builtin_amdgcn_global_load_lds(
                (const __attribute__((address_space(1))) unsigned int*)g,
                (__attribute__((address_space(3))) unsigned int*)&Abuf[(wave * 16 + i * 4) * 128],
                16, 0, 0);
        }
        __syncthreads();                 // staging visible (vmcnt drained)

#pragma unroll
        for (int ksl = 0; ksl < 4; ++ksl) {
            const int ks = c * 4 + ksl;
            bf16x8 a[2];
#pragma unroll
            for (int st = 0; st < 2; ++st) {
                const int r = wm * 32 + st * 16 + ln16;
                const int u = (ksl * 4 + qk) ^ (r & 15);
                a[st] = *(const bf16x8*)&Abuf[r * 128 + u * 8];
            }
#pragma unroll
            for (int nt = 0; nt < 4; ++nt) {
                const int ntg = wn * 4 + nt;
                bf16x8 b = *(const bf16x8*)&Wtf[(size_t)((ntg * 32 + ks) * 64 + lane) * 8];
                acc[0][nt] = __builtin_amdgcn_mfma_f32_16x16x32_bf16(a[0], b, acc[0][nt], 0, 0, 0);
                acc[1][nt] = __builtin_amdgcn_mfma_f32_16x16x32_bf16(a[1], b, acc[1][nt], 0, 0, 0);
            }
        }
    }

    // D layout: col = lane&15, row = (lane>>4)*4 + reg
#pragma unroll
    for (int nt = 0; nt < 4; ++nt) {
        const int o = (wn * 4 + nt) * 16 + ln16;
        const float bv = bias[o];
#pragma unroll
        for (int st = 0; st < 2; ++st)
#pragma unroll
            for (int j = 0; j < 4; ++j) {
                const int t = m0 + wm * 32 + st * 16 + qk * 4 + j;
                if (t < N_NODES) out[(size_t)t * OUT_DIM + o] = acc[st][nt][j] + bv;
            }
    }
}

extern "C" void kernel_launch(void* const* d_in, const int* in_sizes, int n_in,
                              void* d_out, int out_size, void* d_ws, size_t ws_size,
                              hipStream_t stream)
{
    const int*   tri      = (const int*)d_in[0];
    const float* features = (const float*)d_in[1];
    const float* W        = (const float*)d_in[2];
    const float* bias     = (const float*)d_in[3];
    float* out = (float*)d_out;

    char* ws = (char*)d_ws;
    unsigned short* Wtf = (unsigned short*)ws; ws += (size_t)OUT_DIM * KDIM * 2;  // 256 KB
    int* cnt       = (int*)ws; ws += (size_t)NR * 4;
    int* segOff    = (int*)ws; ws += (size_t)(NR + 1) * 4;
    int* cursor    = (int*)ws; ws += (size_t)NR * 4;
    int* bsum      = (int*)ws; ws += (size_t)SCAN_NBLK * 4;
    int* boff      = (int*)ws; ws += (size_t)SCAN_NBLK * 4;
    int* sortedSrc = (int*)ws; ws += (size_t)N_EDGES * 4;
    unsigned short* featB = (unsigned short*)ws; ws += (size_t)N_NODES * IN_DIM * 2;  // 12.8 MB
    unsigned short* aggG  = (unsigned short*)ws; ws += (size_t)M_PAD * KDIM * 2;      // 102.5 MB
    (void)ws_size; (void)in_sizes; (void)n_in; (void)out_size;

    hipMemsetAsync(cnt, 0, NR * sizeof(int), stream);
    prep_kernel<<<CNT_BLKS + CW_BLKS + FB_BLKS, 256, 0, stream>>>(tri, W, features, cnt, Wtf, featB);
    scan_part<<<SCAN_NBLK, 256, 0, stream>>>(cnt, bsum);
    scan_mid<<<1, 256, 0, stream>>>(bsum, boff);
    scan_apply<<<SCAN_NBLK, 256, 0, stream>>>(cnt, boff, segOff, cursor);
    scatter_kernel<<<CNT_BLKS, 256, 0, stream>>>(tri, cursor, sortedSrc);
    agg_kernel<<<N_NODES / 4, 256, 0, stream>>>(sortedSrc, segOff, featB, aggG);
    gemm_kernel<<<M_PAD / 64, 256, 0, stream>>>(aggG, Wtf, bias, out);
}